// Round 1
// 2431.657 us; speedup vs baseline: 1.0946x; 1.0946x over previous
//
#include <hip/hip_runtime.h>
#include <hip/hip_bf16.h>
#include <math.h>

#define NLAYERS 8
#define DMODEL 1024
#define NH 16
#define HD 64
#define FFD 4096
#define SEQ 1024
#define BATCH 2
#define MROWS (BATCH * SEQ)   // 2048
#define LNEPS 1e-5f
#define LDQ 3072              // fused qkv row stride

typedef short bf16x8 __attribute__((ext_vector_type(8)));
typedef float f32x4 __attribute__((ext_vector_type(4)));

__device__ __forceinline__ unsigned short f2bf(float v) {
    unsigned u = __float_as_uint(v);
    u += 0x7fffu + ((u >> 16) & 1u);   // RNE
    return (unsigned short)(u >> 16);
}

__device__ __forceinline__ float gelu_exact(float x) {
    return 0.5f * x * (1.0f + erff(x * 0.70710678118654752f));
}

// async global->LDS, 16B per lane. LDS dest must be linear in lane order
// (wave-uniform base + lane*16) -- our staging layout is byte 16*tid, OK.
__device__ __forceinline__ void glds16(const short* g, short* l) {
    __builtin_amdgcn_global_load_lds(
        (const __attribute__((address_space(1))) unsigned*)g,
        (__attribute__((address_space(3))) unsigned*)l, 16, 0, 0);
}

// ---------------------------------------------------------------- MFMA GEMM (TN)
// C[M,N] = A[M,K] (bf16, row-major) @ Bt[N,K]^T (bf16) + bias.
// m97 structure: global_load_lds width-16 staging, single LDS buffer,
// 2 barriers per K-step. BM=128 always; BN templated (64 for N=1024 GEMMs
// so the grid reaches 256 workgroups instead of 128).
#define TKT 32

template<int BN>
__global__ __launch_bounds__(256) void gemm_tn(
    const short* __restrict__ A, const short* __restrict__ Bt,
    const float* __restrict__ bias, float* __restrict__ Cf,
    short* __restrict__ Cb, int M, int N, int K, int ldc, int act)
{
    constexpr int BM = 128;
    constexpr int MR = (BN == 128) ? 4 : 2;   // 16-row frags per wave
    constexpr int NR = 4;                     // 16-col frags per wave
    __shared__ __align__(16) short As[BM * TKT];
    __shared__ __align__(16) short Bs[BN * TKT];

    const int tid = threadIdx.x;
    const int bm = blockIdx.y * BM;
    const int bn = blockIdx.x * BN;
    const int wave = tid >> 6, lane = tid & 63;
    const int lr = lane & 15, quad = lane >> 4;
    // wave -> output sub-tile
    const int wm = (BN == 128) ? ((wave >> 1) << 6) : (wave << 5);
    const int wn = (BN == 128) ? ((wave & 1) << 6) : 0;

    const int srow = tid >> 2;            // 0..63
    const int scol = (tid & 3) << 3;      // 0,8,16,24 (bf16 elems)
    const short* ag = A  + (size_t)(bm + srow) * K + scol;
    const short* bg = Bt + (size_t)(bn + srow) * K + scol;
    short* asl = As + srow * TKT + scol;  // byte offset 16*tid: linear in lane order
    short* bsl = Bs + srow * TKT + scol;

    f32x4 acc[MR][NR] = {};
    for (int k0 = 0; k0 < K; k0 += TKT) {
        __syncthreads();                  // all waves done reading LDS tile k-1
        glds16(ag + k0, asl);
        glds16(ag + (size_t)64 * K + k0, asl + 64 * TKT);
        glds16(bg + k0, bsl);
        if constexpr (BN == 128)
            glds16(bg + (size_t)64 * K + k0, bsl + 64 * TKT);
        __syncthreads();                  // vmcnt(0) drained by barrier -> LDS ready

        bf16x8 af[MR], bfr[NR];
#pragma unroll
        for (int i = 0; i < MR; ++i)
            af[i]  = *(const bf16x8*)(As + (wm + i * 16 + lr) * TKT + (quad << 3));
#pragma unroll
        for (int j = 0; j < NR; ++j)
            bfr[j] = *(const bf16x8*)(Bs + (wn + j * 16 + lr) * TKT + (quad << 3));
#pragma unroll
        for (int i = 0; i < MR; ++i)
#pragma unroll
            for (int j = 0; j < NR; ++j)
                acc[i][j] = __builtin_amdgcn_mfma_f32_16x16x32_bf16(
                    af[i], bfr[j], acc[i][j], 0, 0, 0);
    }
#pragma unroll
    for (int j = 0; j < NR; ++j) {
        const int col = bn + wn + j * 16 + lr;
        const float bj = bias[col];
#pragma unroll
        for (int i = 0; i < MR; ++i) {
            const int rowb = bm + wm + i * 16 + (quad << 2);
#pragma unroll
            for (int r = 0; r < 4; ++r) {
                float v = acc[i][j][r] + bj;
                if (act) v = gelu_exact(v);
                if (Cb) Cb[(size_t)(rowb + r) * ldc + col] = (short)f2bf(v);
                else    Cf[(size_t)(rowb + r) * ldc + col] = v;
            }
        }
    }
}

// ---------------------------------------------------------------- transpose + fp32->bf16
__global__ __launch_bounds__(256) void transpose_bf16(
    const float* __restrict__ in, short* __restrict__ out, int R, int C)
{
    __shared__ float t[32][33];
    const int tid = threadIdx.x;
    const int rt = blockIdx.y << 5, ct = blockIdx.x << 5;
    const int r = tid >> 3, c4 = (tid & 7) << 2;
    float4 v = *(const float4*)(in + (size_t)(rt + r) * C + ct + c4);
    t[r][c4 + 0] = v.x; t[r][c4 + 1] = v.y; t[r][c4 + 2] = v.z; t[r][c4 + 3] = v.w;
    __syncthreads();
    unsigned short s0 = f2bf(t[c4 + 0][r]);
    unsigned short s1 = f2bf(t[c4 + 1][r]);
    unsigned short s2 = f2bf(t[c4 + 2][r]);
    unsigned short s3 = f2bf(t[c4 + 3][r]);
    uint2 p;
    p.x = (unsigned)s0 | ((unsigned)s1 << 16);
    p.y = (unsigned)s2 | ((unsigned)s3 << 16);
    *(uint2*)(out + (size_t)(ct + r) * R + rt + c4) = p;
}

// ---------------------------------------------------------------- small utils
__global__ void stack_bias(const float* __restrict__ bq, const float* __restrict__ bk,
                           const float* __restrict__ bv, float* __restrict__ out)
{
    int i = blockIdx.x * 256 + threadIdx.x;   // 0..3071
    float v = (i < 1024) ? bq[i] : (i < 2048) ? bk[i - 1024] : bv[i - 2048];
    out[i] = v;
}

__global__ void conv_bf16(const float* __restrict__ in, short* __restrict__ out, int n)
{
    int i = (blockIdx.x * 256 + threadIdx.x) << 2;
    if (i < n) {
        float4 v = *(const float4*)(in + i);
        uint2 p;
        p.x = (unsigned)f2bf(v.x) | ((unsigned)f2bf(v.y) << 16);
        p.y = (unsigned)f2bf(v.z) | ((unsigned)f2bf(v.w) << 16);
        *(uint2*)(out + i) = p;
    }
}

// ---------------------------------------------------------------- PE table
__global__ void pe_fill(float* __restrict__ pe)
{
    int pos = blockIdx.x;
    int i = threadIdx.x;            // 0..63
    int j = i & 31;
    float invf = powf(10000.0f, -(float)j / 32.0f);
    float a = (float)pos * invf;
    pe[pos * HD + i] = (i < 32) ? cosf(a) : sinf(a);
}

// ---------------------------------------------------------------- RoPE on fused qkv
__global__ __launch_bounds__(64) void rope_kernel(
    float* __restrict__ xqkv, const float* __restrict__ pe)
{
    float* base = xqkv + (blockIdx.y ? DMODEL : 0);
    int bid = blockIdx.x;           // row*NH + h
    int h = bid & (NH - 1);
    int row = bid >> 4;             // b*SEQ + l
    int pos = row & (SEQ - 1);
    __shared__ float xv[HD];
    float* p = base + (size_t)row * LDQ + h * HD;
    int d = threadIdx.x;
    xv[d] = p[d];
    __syncthreads();
    const float* pr = pe + pos * HD;
    float out;
    if (d < 32) {
        out = xv[2 * d] * pr[2 * d] - xv[2 * d + 1] * pr[2 * d + 1];
    } else {
        int j = d - 32;
        out = xv[2 * j] * pr[2 * j + 1] + xv[2 * j + 1] * pr[2 * j];
    }
    p[d] = out;
}

// ---------------------------------------------------------------- MFMA flash attention
#define ATQ 64
#define ATK 64
#define APAD 72

__global__ __launch_bounds__(256) void attn_mfma(
    const float* __restrict__ xqkv, short* __restrict__ ob)
{
    __shared__ __align__(16) short Qs[ATQ * APAD];
    __shared__ __align__(16) short Ks[ATK * APAD];
    __shared__ __align__(16) short Vt[HD * APAD];
    __shared__ __align__(16) short Ps[4 * 16 * APAD];

    const int tid = threadIdx.x;
    const int bid = blockIdx.x;
    const int qtile = bid & 15;
    const int h = (bid >> 4) & 15;
    const int b = bid >> 8;
    const int q0 = qtile * ATQ;
    const size_t hoff = (size_t)h * HD;
    const float* qg = xqkv;
    const float* kg = xqkv + DMODEL;
    const float* vg = xqkv + 2 * DMODEL;

    const int wave = tid >> 6, lane = tid & 63;
    const int lr = lane & 15, quad = lane >> 4;
    const int srow = tid >> 2;          // 0..63
    const int sc0 = (tid & 3) << 4;     // 0,16,32,48

    // ---- stage Q once (fp32 -> bf16)
    {
        const float* p = qg + (size_t)(b * SEQ + q0 + srow) * LDQ + hoff + sc0;
        float4 v0 = *(const float4*)(p);
        float4 v1 = *(const float4*)(p + 4);
        float4 v2 = *(const float4*)(p + 8);
        float4 v3 = *(const float4*)(p + 12);
        bf16x8 a, c;
        a[0] = f2bf(v0.x); a[1] = f2bf(v0.y); a[2] = f2bf(v0.z); a[3] = f2bf(v0.w);
        a[4] = f2bf(v1.x); a[5] = f2bf(v1.y); a[6] = f2bf(v1.z); a[7] = f2bf(v1.w);
        c[0] = f2bf(v2.x); c[1] = f2bf(v2.y); c[2] = f2bf(v2.z); c[3] = f2bf(v2.w);
        c[4] = f2bf(v3.x); c[5] = f2bf(v3.y); c[6] = f2bf(v3.z); c[7] = f2bf(v3.w);
        *(bf16x8*)(Qs + srow * APAD + sc0) = a;
        *(bf16x8*)(Qs + srow * APAD + sc0 + 8) = c;
    }
    __syncthreads();
    const bf16x8 qf0 = *(const bf16x8*)(Qs + (wave * 16 + lr) * APAD + (quad << 3));
    const bf16x8 qf1 = *(const bf16x8*)(Qs + (wave * 16 + lr) * APAD + 32 + (quad << 3));

    const float slope = exp2f(-0.5f * (float)h);
    const int qpos = q0 + wave * 16 + quad * 4;   // +r
    float mrow[4] = {-INFINITY, -INFINITY, -INFINITY, -INFINITY};
    float lrow[4] = {0.f, 0.f, 0.f, 0.f};
    f32x4 oacc[4] = {};

    for (int kt0 = 0; kt0 < SEQ; kt0 += ATK) {
        __syncthreads();
        // ---- stage K tile
        {
            const float* p = kg + (size_t)(b * SEQ + kt0 + srow) * LDQ + hoff + sc0;
            float4 v0 = *(const float4*)(p);
            float4 v1 = *(const float4*)(p + 4);
            float4 v2 = *(const float4*)(p + 8);
            float4 v3 = *(const float4*)(p + 12);
            bf16x8 a, c;
            a[0] = f2bf(v0.x); a[1] = f2bf(v0.y); a[2] = f2bf(v0.z); a[3] = f2bf(v0.w);
            a[4] = f2bf(v1.x); a[5] = f2bf(v1.y); a[6] = f2bf(v1.z); a[7] = f2bf(v1.w);
            c[0] = f2bf(v2.x); c[1] = f2bf(v2.y); c[2] = f2bf(v2.z); c[3] = f2bf(v2.w);
            c[4] = f2bf(v3.x); c[5] = f2bf(v3.y); c[6] = f2bf(v3.z); c[7] = f2bf(v3.w);
            *(bf16x8*)(Ks + srow * APAD + sc0) = a;
            *(bf16x8*)(Ks + srow * APAD + sc0 + 8) = c;
        }
        // ---- stage V tile transposed: Vt[hd][key]
        {
            const float* p = vg + (size_t)(b * SEQ + kt0 + srow) * LDQ + hoff + sc0;
            float4 v0 = *(const float4*)(p);
            float4 v1 = *(const float4*)(p + 4);
            float4 v2 = *(const float4*)(p + 8);
            float4 v3 = *(const float4*)(p + 12);
            float a[16] = {v0.x, v0.y, v0.z, v0.w, v1.x, v1.y, v1.z, v1.w,
                           v2.x, v2.y, v2.z, v2.w, v3.x, v3.y, v3.z, v3.w};
#pragma unroll
            for (int i = 0; i < 16; ++i)
                Vt[(sc0 + i) * APAD + srow] = (short)f2bf(a[i]);
        }
        __syncthreads();

        // ---- S = Q K^T  (4 j-tiles of 16 keys)
        f32x4 s[4] = {};
#pragma unroll
        for (int j = 0; j < 4; ++j) {
            bf16x8 b0 = *(const bf16x8*)(Ks + (j * 16 + lr) * APAD + (quad << 3));
            bf16x8 b1 = *(const bf16x8*)(Ks + (j * 16 + lr) * APAD + 32 + (quad << 3));
            s[j] = __builtin_amdgcn_mfma_f32_16x16x32_bf16(qf0, b0, s[j], 0, 0, 0);
            s[j] = __builtin_amdgcn_mfma_f32_16x16x32_bf16(qf1, b1, s[j], 0, 0, 0);
        }

        // ---- bias + online softmax (rows quad*4+r, cols j*16+lr)
        float pv[4][4];
        float rmax[4] = {-INFINITY, -INFINITY, -INFINITY, -INFINITY};
#pragma unroll
        for (int j = 0; j < 4; ++j) {
            const int kpos = kt0 + j * 16 + lr;
#pragma unroll
            for (int r = 0; r < 4; ++r) {
                float dist = (float)(qpos + r - kpos);
                float val = s[j][r] * 0.125f + slope * fmaxf(dist, 0.0f);
                pv[j][r] = val;
                rmax[r] = fmaxf(rmax[r], val);
            }
        }
#pragma unroll
        for (int off = 1; off <= 8; off <<= 1) {
#pragma unroll
            for (int r = 0; r < 4; ++r)
                rmax[r] = fmaxf(rmax[r], __shfl_xor(rmax[r], off));
        }
        float alpha[4], rsum[4] = {0.f, 0.f, 0.f, 0.f};
#pragma unroll
        for (int r = 0; r < 4; ++r) {
            float mnew = fmaxf(mrow[r], rmax[r]);
            alpha[r] = __expf(mrow[r] - mnew);
            mrow[r] = mnew;
        }
#pragma unroll
        for (int j = 0; j < 4; ++j)
#pragma unroll
            for (int r = 0; r < 4; ++r) {
                float e = __expf(pv[j][r] - mrow[r]);
                pv[j][r] = e;
                rsum[r] += e;
            }
#pragma unroll
        for (int off = 1; off <= 8; off <<= 1) {
#pragma unroll
            for (int r = 0; r < 4; ++r)
                rsum[r] += __shfl_xor(rsum[r], off);
        }
#pragma unroll
        for (int r = 0; r < 4; ++r)
            lrow[r] = lrow[r] * alpha[r] + rsum[r];
#pragma unroll
        for (int n = 0; n < 4; ++n)
#pragma unroll
            for (int r = 0; r < 4; ++r)
                oacc[n][r] *= alpha[r];

        // ---- P -> LDS (C-layout -> A-operand layout round trip)
#pragma unroll
        for (int j = 0; j < 4; ++j)
#pragma unroll
            for (int r = 0; r < 4; ++r)
                Ps[(wave * 16 + quad * 4 + r) * APAD + j * 16 + lr] = (short)f2bf(pv[j][r]);
        __syncthreads();

        // ---- O += P V
        bf16x8 p0 = *(const bf16x8*)(Ps + (wave * 16 + lr) * APAD + (quad << 3));
        bf16x8 p1 = *(const bf16x8*)(Ps + (wave * 16 + lr) * APAD + 32 + (quad << 3));
#pragma unroll
        for (int n = 0; n < 4; ++n) {
            bf16x8 b0 = *(const bf16x8*)(Vt + (n * 16 + lr) * APAD + (quad << 3));
            bf16x8 b1 = *(const bf16x8*)(Vt + (n * 16 + lr) * APAD + 32 + (quad << 3));
            oacc[n] = __builtin_amdgcn_mfma_f32_16x16x32_bf16(p0, b0, oacc[n], 0, 0, 0);
            oacc[n] = __builtin_amdgcn_mfma_f32_16x16x32_bf16(p1, b1, oacc[n], 0, 0, 0);
        }
    }

    // ---- epilogue: normalize, write bf16
    float inv[4];
#pragma unroll
    for (int r = 0; r < 4; ++r) inv[r] = 1.0f / lrow[r];
#pragma unroll
    for (int n = 0; n < 4; ++n)
#pragma unroll
        for (int r = 0; r < 4; ++r)
            ob[(size_t)(b * SEQ + qpos + r) * DMODEL + hoff + n * 16 + lr] =
                (short)f2bf(oacc[n][r] * inv[r]);
}

// ---------------------------------------------------------------- residual + LayerNorm (+ bf16 mirror)
__global__ __launch_bounds__(256) void add_ln_kernel(
    const float* __restrict__ x, const float* __restrict__ r,
    const float* __restrict__ g, const float* __restrict__ b,
    float* __restrict__ out, short* __restrict__ outb)
{
    __shared__ float rs[4], rq[4], stats[2];
    const int row = blockIdx.x, tid = threadIdx.x;
    const int c = tid << 2;
    float4 v = *(const float4*)(x + (size_t)row * DMODEL + c);
    if (r) {
        float4 rv = *(const float4*)(r + (size_t)row * DMODEL + c);
        v.x += rv.x; v.y += rv.y; v.z += rv.z; v.w += rv.w;
    }
    float s = v.x + v.y + v.z + v.w;
    float q2 = v.x * v.x + v.y * v.y + v.z * v.z + v.w * v.w;
#pragma unroll
    for (int off = 32; off; off >>= 1) {
        s += __shfl_down(s, off, 64);
        q2 += __shfl_down(q2, off, 64);
    }
    const int wid = tid >> 6, lane = tid & 63;
    if (lane == 0) { rs[wid] = s; rq[wid] = q2; }
    __syncthreads();
    if (tid == 0) {
        float ts = rs[0] + rs[1] + rs[2] + rs[3];
        float tq = rq[0] + rq[1] + rq[2] + rq[3];
        float mean = ts * (1.0f / DMODEL);
        stats[0] = mean;
        stats[1] = rsqrtf(tq * (1.0f / DMODEL) - mean * mean + LNEPS);
    }
    __syncthreads();
    const float mean = stats[0], rstd = stats[1];
    float4 gv = *(const float4*)(g + c);
    float4 bv = *(const float4*)(b + c);
    float4 res;
    res.x = (v.x - mean) * rstd * gv.x + bv.x;
    res.y = (v.y - mean) * rstd * gv.y + bv.y;
    res.z = (v.z - mean) * rstd * gv.z + bv.z;
    res.w = (v.w - mean) * rstd * gv.w + bv.w;
    *(float4*)(out + (size_t)row * DMODEL + c) = res;
    if (outb) {
        uint2 p;
        p.x = (unsigned)f2bf(res.x) | ((unsigned)f2bf(res.y) << 16);
        p.y = (unsigned)f2bf(res.z) | ((unsigned)f2bf(res.w) << 16);
        *(uint2*)(outb + (size_t)row * DMODEL + c) = p;
    }
}

// ---------------------------------------------------------------- host
extern "C" void kernel_launch(void* const* d_in, const int* in_sizes, int n_in,
                              void* d_out, int out_size, void* d_ws, size_t ws_size,
                              hipStream_t stream)
{
    (void)in_sizes; (void)n_in; (void)out_size; (void)ws_size;
    const float* src = (const float*)d_in[0];
    const float* Wq  = (const float*)d_in[1];
    const float* bq  = (const float*)d_in[2];
    const float* Wk  = (const float*)d_in[3];
    const float* bk  = (const float*)d_in[4];
    const float* Wv  = (const float*)d_in[5];
    const float* bv  = (const float*)d_in[6];
    const float* Wo  = (const float*)d_in[7];
    const float* bo  = (const float*)d_in[8];
    const float* W1  = (const float*)d_in[9];
    const float* b1  = (const float*)d_in[10];
    const float* W2  = (const float*)d_in[11];
    const float* b2  = (const float*)d_in[12];
    const float* g1  = (const float*)d_in[13];
    const float* be1 = (const float*)d_in[14];
    const float* g2  = (const float*)d_in[15];
    const float* be2 = (const float*)d_in[16];
    const float* gf  = (const float*)d_in[17];
    const float* bfp = (const float*)d_in[18];
    float* out = (float*)d_out;

    char* p = (char*)d_ws;
    auto carve = [&](size_t bytes) -> char* {
        char* r = p; p += (bytes + 255) & ~(size_t)255; return r;
    };
    float* x    = (float*)carve((size_t)MROWS * DMODEL * 4);
    float* t1   = (float*)carve((size_t)MROWS * DMODEL * 4);
    float* xqkv = (float*)carve((size_t)MROWS * LDQ * 4);
    float* pe   = (float*)carve((size_t)SEQ * HD * 4);
    float* bqkv = (float*)carve((size_t)LDQ * 4);
    short* xb   = (short*)carve((size_t)MROWS * DMODEL * 2);
    short* obb  = (short*)carve((size_t)MROWS * DMODEL * 2);
    short* h1b  = (short*)carve((size_t)MROWS * FFD * 2);
    short* wtqkv= (short*)carve((size_t)3 * DMODEL * DMODEL * 2);
    short* wto  = (short*)carve((size_t)DMODEL * DMODEL * 2);
    short* wt1  = (short*)carve((size_t)DMODEL * FFD * 2);
    short* wt2  = (short*)carve((size_t)DMODEL * FFD * 2);

    hipMemcpyAsync(x, src, (size_t)MROWS * DMODEL * 4, hipMemcpyDeviceToDevice, stream);
    conv_bf16<<<MROWS * DMODEL / 4 / 256, 256, 0, stream>>>(src, xb, MROWS * DMODEL);
    pe_fill<<<SEQ, HD, 0, stream>>>(pe);

    const size_t DD = (size_t)DMODEL * DMODEL;
    for (int l = 0; l < NLAYERS; ++l) {
        transpose_bf16<<<dim3(32, 32), 256, 0, stream>>>(Wq + l * DD, wtqkv,          DMODEL, DMODEL);
        transpose_bf16<<<dim3(32, 32), 256, 0, stream>>>(Wk + l * DD, wtqkv + DD,     DMODEL, DMODEL);
        transpose_bf16<<<dim3(32, 32), 256, 0, stream>>>(Wv + l * DD, wtqkv + 2 * DD, DMODEL, DMODEL);
        transpose_bf16<<<dim3(32, 32), 256, 0, stream>>>(Wo + l * DD, wto, DMODEL, DMODEL);
        transpose_bf16<<<dim3(128, 32), 256, 0, stream>>>(W1 + (size_t)l * DMODEL * FFD, wt1, DMODEL, FFD);
        transpose_bf16<<<dim3(32, 128), 256, 0, stream>>>(W2 + (size_t)l * FFD * DMODEL, wt2, FFD, DMODEL);
        stack_bias<<<12, 256, 0, stream>>>(bq + l * DMODEL, bk + l * DMODEL, bv + l * DMODEL, bqkv);

        gemm_tn<128><<<dim3(LDQ / 128, MROWS / 128), 256, 0, stream>>>(
            xb, wtqkv, bqkv, xqkv, nullptr, MROWS, LDQ, DMODEL, LDQ, 0);
        rope_kernel<<<dim3(MROWS * NH, 2), 64, 0, stream>>>(xqkv, pe);
        attn_mfma<<<BATCH * NH * (SEQ / ATQ), 256, 0, stream>>>(xqkv, obb);
        gemm_tn<64><<<dim3(DMODEL / 64, MROWS / 128), 256, 0, stream>>>(
            obb, wto, bo + l * DMODEL, t1, nullptr, MROWS, DMODEL, DMODEL, DMODEL, 0);
        add_ln_kernel<<<MROWS, 256, 0, stream>>>(x, t1, g1 + l * DMODEL, be1 + l * DMODEL, x, xb);
        gemm_tn<128><<<dim3(FFD / 128, MROWS / 128), 256, 0, stream>>>(
            xb, wt1, b1 + l * FFD, nullptr, h1b, MROWS, FFD, DMODEL, FFD, 1);
        gemm_tn<64><<<dim3(DMODEL / 64, MROWS / 128), 256, 0, stream>>>(
            h1b, wt2, b2 + l * DMODEL, t1, nullptr, MROWS, DMODEL, FFD, DMODEL, 0);
        add_ln_kernel<<<MROWS, 256, 0, stream>>>(x, t1, g2 + l * DMODEL, be2 + l * DMODEL, x, xb);
    }
    add_ln_kernel<<<MROWS, 256, 0, stream>>>(x, nullptr, gf, bfp, out, nullptr);
}

// Round 2
// 2159.405 us; speedup vs baseline: 1.2326x; 1.1261x over previous
//
#include <hip/hip_runtime.h>
#include <hip/hip_bf16.h>
#include <math.h>

#define NLAYERS 8
#define DMODEL 1024
#define NH 16
#define HD 64
#define FFD 4096
#define SEQ 1024
#define BATCH 2
#define MROWS (BATCH * SEQ)   // 2048
#define LNEPS 1e-5f
#define LDQ 3072              // fused qkv row stride

typedef short bf16x8 __attribute__((ext_vector_type(8)));
typedef float f32x4 __attribute__((ext_vector_type(4)));

__device__ __forceinline__ unsigned short f2bf(float v) {
    unsigned u = __float_as_uint(v);
    u += 0x7fffu + ((u >> 16) & 1u);   // RNE
    return (unsigned short)(u >> 16);
}

__device__ __forceinline__ float gelu_exact(float x) {
    return 0.5f * x * (1.0f + erff(x * 0.70710678118654752f));
}

// async global->LDS, 16B per lane. LDS dest must be linear in lane order.
__device__ __forceinline__ void glds16(const short* g, short* l) {
    __builtin_amdgcn_global_load_lds(
        (const __attribute__((address_space(1))) unsigned*)g,
        (__attribute__((address_space(3))) unsigned*)l, 16, 0, 0);
}

// ---------------------------------------------------------------- MFMA GEMM (TN)
// C[M,N] = A[M,K] (bf16, row-major) @ Bt[N,K]^T (bf16) + bias.
// Double-buffered LDS, global_load_lds staging of tile t+1 issued BEFORE
// the MFMA of tile t; raw s_barrier + explicit vmcnt(0) after compute so
// the prefetch overlaps MFMA (T3-minimum 2-phase).
#define TKT 32

template<int BN>
__global__ __launch_bounds__(256) void gemm_tn(
    const short* __restrict__ A, const short* __restrict__ Bt,
    const float* __restrict__ bias, float* __restrict__ Cf,
    short* __restrict__ Cb, int M, int N, int K, int ldc, int act)
{
    constexpr int BM = 128;
    constexpr int MR = (BN == 128) ? 4 : 2;   // 16-row frags per wave
    constexpr int NR = 4;                     // 16-col frags per wave
    __shared__ __align__(16) short As[2][BM * TKT];
    __shared__ __align__(16) short Bs[2][BN * TKT];

    const int tid = threadIdx.x;
    const int bm = blockIdx.y * BM;
    const int bn = blockIdx.x * BN;
    const int wave = tid >> 6, lane = tid & 63;
    const int lr = lane & 15, quad = lane >> 4;
    const int wm = (BN == 128) ? ((wave >> 1) << 6) : (wave << 5);
    const int wn = (BN == 128) ? ((wave & 1) << 6) : 0;

    const int srow = tid >> 2;            // 0..63
    const int scol = (tid & 3) << 3;      // 0,8,16,24 (bf16 elems)
    const short* ag = A  + (size_t)(bm + srow) * K + scol;
    const short* bg = Bt + (size_t)(bn + srow) * K + scol;
    const int soff = srow * TKT + scol;   // = tid*8 shorts: linear in lane order

    f32x4 acc[MR][NR] = {};
    const int nk = K / TKT;

    // prologue: stage tile 0
    glds16(ag, As[0] + soff);
    glds16(ag + (size_t)64 * K, As[0] + soff + 64 * TKT);
    glds16(bg, Bs[0] + soff);
    if constexpr (BN == 128) glds16(bg + (size_t)64 * K, Bs[0] + soff + 64 * TKT);
    asm volatile("s_waitcnt vmcnt(0)" ::: "memory");
    __builtin_amdgcn_s_barrier();

    for (int t = 0; t < nk; ++t) {
        const int cur = t & 1;
        if (t + 1 < nk) {                 // prefetch tile t+1 (overlaps MFMA below)
            const int k0 = (t + 1) * TKT;
            glds16(ag + k0, As[cur ^ 1] + soff);
            glds16(ag + (size_t)64 * K + k0, As[cur ^ 1] + soff + 64 * TKT);
            glds16(bg + k0, Bs[cur ^ 1] + soff);
            if constexpr (BN == 128)
                glds16(bg + (size_t)64 * K + k0, Bs[cur ^ 1] + soff + 64 * TKT);
        }
        bf16x8 af[MR], bfr[NR];
#pragma unroll
        for (int i = 0; i < MR; ++i)
            af[i]  = *(const bf16x8*)(As[cur] + (wm + i * 16 + lr) * TKT + (quad << 3));
#pragma unroll
        for (int j = 0; j < NR; ++j)
            bfr[j] = *(const bf16x8*)(Bs[cur] + (wn + j * 16 + lr) * TKT + (quad << 3));
#pragma unroll
        for (int i = 0; i < MR; ++i)
#pragma unroll
            for (int j = 0; j < NR; ++j)
                acc[i][j] = __builtin_amdgcn_mfma_f32_16x16x32_bf16(
                    af[i], bfr[j], acc[i][j], 0, 0, 0);
        asm volatile("s_waitcnt vmcnt(0)" ::: "memory");   // t+1 loads landed
        __builtin_amdgcn_s_barrier();
    }
#pragma unroll
    for (int j = 0; j < NR; ++j) {
        const int col = bn + wn + j * 16 + lr;
        const float bj = bias[col];
#pragma unroll
        for (int i = 0; i < MR; ++i) {
            const int rowb = bm + wm + i * 16 + (quad << 2);
#pragma unroll
            for (int r = 0; r < 4; ++r) {
                float v = acc[i][j][r] + bj;
                if (act) v = gelu_exact(v);
                if (Cb) Cb[(size_t)(rowb + r) * ldc + col] = (short)f2bf(v);
                else    Cf[(size_t)(rowb + r) * ldc + col] = v;
            }
        }
    }
}

// ---------------------------------------------------------------- transpose + fp32->bf16
__global__ __launch_bounds__(256) void transpose_bf16(
    const float* __restrict__ in, short* __restrict__ out, int R, int C)
{
    __shared__ float t[32][33];
    const int tid = threadIdx.x;
    const int rt = blockIdx.y << 5, ct = blockIdx.x << 5;
    const int r = tid >> 3, c4 = (tid & 7) << 2;
    float4 v = *(const float4*)(in + (size_t)(rt + r) * C + ct + c4);
    t[r][c4 + 0] = v.x; t[r][c4 + 1] = v.y; t[r][c4 + 2] = v.z; t[r][c4 + 3] = v.w;
    __syncthreads();
    unsigned short s0 = f2bf(t[c4 + 0][r]);
    unsigned short s1 = f2bf(t[c4 + 1][r]);
    unsigned short s2 = f2bf(t[c4 + 2][r]);
    unsigned short s3 = f2bf(t[c4 + 3][r]);
    uint2 p;
    p.x = (unsigned)s0 | ((unsigned)s1 << 16);
    p.y = (unsigned)s2 | ((unsigned)s3 << 16);
    *(uint2*)(out + (size_t)(ct + r) * R + rt + c4) = p;
}

// ---------------------------------------------------------------- small utils
__global__ void stack_bias(const float* __restrict__ bq, const float* __restrict__ bk,
                           const float* __restrict__ bv, float* __restrict__ out)
{
    int i = blockIdx.x * 256 + threadIdx.x;   // 0..3071
    float v = (i < 1024) ? bq[i] : (i < 2048) ? bk[i - 1024] : bv[i - 2048];
    out[i] = v;
}

__global__ void conv_bf16(const float* __restrict__ in, short* __restrict__ out, int n)
{
    int i = (blockIdx.x * 256 + threadIdx.x) << 2;
    if (i < n) {
        float4 v = *(const float4*)(in + i);
        uint2 p;
        p.x = (unsigned)f2bf(v.x) | ((unsigned)f2bf(v.y) << 16);
        p.y = (unsigned)f2bf(v.z) | ((unsigned)f2bf(v.w) << 16);
        *(uint2*)(out + i) = p;
    }
}

// ---------------------------------------------------------------- PE table
__global__ void pe_fill(float* __restrict__ pe)
{
    int pos = blockIdx.x;
    int i = threadIdx.x;            // 0..63
    int j = i & 31;
    float invf = powf(10000.0f, -(float)j / 32.0f);
    float a = (float)pos * invf;
    pe[pos * HD + i] = (i < 32) ? cosf(a) : sinf(a);
}

// ---------------------------------------------------------------- RoPE + bf16 convert + V transpose
// Reads fused qkv (fp32), writes:
//   Qb,Kb : [B][H][S][64] bf16, roped, rows XOR-swizzled (chunk16B ^ (s&7)<<4)
//   Vtb   : [B][H][64][S] bf16, transposed, 128B tile-segments XOR-swizzled by (hd&7)
// Swizzle lives in GLOBAL layout so attention can global_load_lds linearly
// (rule: linear dest + pre-swizzled source + swizzled LDS read).
__global__ __launch_bounds__(256) void ropeconv(
    const float* __restrict__ xqkv, const float* __restrict__ pe,
    short* __restrict__ Qb, short* __restrict__ Kb, short* __restrict__ Vtb)
{
    __shared__ __align__(16) short Vl[HD * 72];   // [hd][s] transpose staging

    const int stile = blockIdx.x;     // 0..15
    const int h = blockIdx.y;         // 0..15
    const int b = blockIdx.z;         // 0..1
    const int tid = threadIdx.x;
    const int srow = tid >> 2;        // 0..63
    const int c0 = (tid & 3) << 4;    // output head-dims [c0, c0+16)
    const int s = stile * 64 + srow;
    const size_t xoff = (size_t)(b * SEQ + s) * LDQ + h * HD;
    const int e0 = (c0 & 31) << 1;    // input dim base

    const float* px = xqkv + xoff;              // q
    const float* pk = xqkv + DMODEL + xoff;     // k
    const float* pp = pe + s * HD + e0;
    float qv[32], kv[32], pv[32];
#pragma unroll
    for (int i = 0; i < 32; i += 4) {
        *(float4*)(qv + i) = *(const float4*)(px + e0 + i);
        *(float4*)(kv + i) = *(const float4*)(pk + e0 + i);
        *(float4*)(pv + i) = *(const float4*)(pp + i);
    }
    bf16x8 oq[2], ok[2];
#pragma unroll
    for (int i = 0; i < 16; ++i) {
        float qa = qv[2 * i], qb2 = qv[2 * i + 1];
        float ka = kv[2 * i], kb2 = kv[2 * i + 1];
        float cc = pv[2 * i], ss = pv[2 * i + 1];
        float rq = (c0 < 32) ? qa * cc - qb2 * ss : qa * ss + qb2 * cc;
        float rk = (c0 < 32) ? ka * cc - kb2 * ss : ka * ss + kb2 * cc;
        oq[i >> 3][i & 7] = (short)f2bf(rq);
        ok[i >> 3][i & 7] = (short)f2bf(rk);
    }
    const size_t obase = ((size_t)(b * NH + h) * SEQ + s) * HD;
    const int sw = (s & 7) << 3;      // swizzle in shorts
    *(bf16x8*)(Qb + obase + (c0 ^ sw))       = oq[0];
    *(bf16x8*)(Qb + obase + ((c0 + 8) ^ sw)) = oq[1];
    *(bf16x8*)(Kb + obase + (c0 ^ sw))       = ok[0];
    *(bf16x8*)(Kb + obase + ((c0 + 8) ^ sw)) = ok[1];

    // V: convert + transpose via LDS
    {
        const float* pvg = xqkv + 2 * DMODEL + xoff;
        float vv[16];
#pragma unroll
        for (int i = 0; i < 16; i += 4)
            *(float4*)(vv + i) = *(const float4*)(pvg + c0 + i);
#pragma unroll
        for (int i = 0; i < 16; ++i)
            Vl[(c0 + i) * 72 + srow] = (short)f2bf(vv[i]);
    }
    __syncthreads();
    {
        const int r = tid >> 2;               // hd 0..63
        const int cb = (tid & 3) << 4;        // s-chunk base within tile (shorts)
        bf16x8 w0 = *(const bf16x8*)(Vl + r * 72 + cb);
        bf16x8 w1 = *(const bf16x8*)(Vl + r * 72 + cb + 8);
        const int swv = (r & 7) << 3;
        const size_t vb = ((size_t)(b * NH + h) * HD + r) * SEQ + stile * 64;
        *(bf16x8*)(Vtb + vb + (cb ^ swv))       = w0;
        *(bf16x8*)(Vtb + vb + ((cb + 8) ^ swv)) = w1;
    }
}

// ---------------------------------------------------------------- MFMA flash attention
// Block = (b, h, 64-query tile); 4 waves, each owns 16 q-rows.
// Q/K/Vt are pre-converted bf16 in pre-swizzled global layout: staging is
// pure global_load_lds (linear dest), double-buffered, prefetched one tile
// ahead; LDS reads apply the XOR swizzle (conflict-free at 128B row stride).
#define ATQ 64
#define ATK 64
#define APAD 72

__global__ __launch_bounds__(256) void attn_mfma(
    const short* __restrict__ Qb, const short* __restrict__ Kb,
    const short* __restrict__ Vtb, short* __restrict__ ob)
{
    __shared__ __align__(16) short Qs[ATQ * HD];
    __shared__ __align__(16) short Ks[2][ATK * HD];
    __shared__ __align__(16) short Vt[2][HD * ATK];
    __shared__ __align__(16) short Ps[ATQ * APAD];

    const int tid = threadIdx.x;
    const int bid = blockIdx.x;
    const int qtile = bid & 15;
    const int h = (bid >> 4) & 15;
    const int b = bid >> 8;
    const int q0 = qtile * ATQ;
    const int bh = b * NH + h;
    const size_t qbase = ((size_t)bh * SEQ + q0) * HD;
    const size_t kbase = (size_t)bh * SEQ * HD;
    const size_t vbase = (size_t)bh * HD * SEQ;

    const int wave = tid >> 6, lane = tid & 63;
    const int lr = lane & 15, quad = lane >> 4;
    const int dl = tid * 8;            // shorts: linear lane-order LDS dest
    const int vr = tid >> 3;           // 0..31 (row within 32-row half)
    const int vc = (tid & 7) * 8;      // col chunk (shorts)

    // ---- prologue: stage Q + K/V tile 0
    glds16(Qb + qbase + dl, Qs + dl);
    glds16(Qb + qbase + 2048 + dl, Qs + 2048 + dl);
    glds16(Kb + kbase + dl, Ks[0] + dl);
    glds16(Kb + kbase + 32 * HD + dl, Ks[0] + 2048 + dl);
    glds16(Vtb + vbase + (size_t)vr * SEQ + vc, Vt[0] + dl);
    glds16(Vtb + vbase + (size_t)(vr + 32) * SEQ + vc, Vt[0] + 2048 + dl);
    __syncthreads();

    bf16x8 qf0, qf1;
    {
        const int row = wave * 16 + lr;
        const int sw = (row & 7) << 3;
        qf0 = *(const bf16x8*)(Qs + row * HD + ((quad * 8) ^ sw));
        qf1 = *(const bf16x8*)(Qs + row * HD + ((32 + quad * 8) ^ sw));
    }

    const float slope = exp2f(-0.5f * (float)h);
    const int qpos = q0 + wave * 16 + quad * 4;   // +r
    float mrow[4] = {-INFINITY, -INFINITY, -INFINITY, -INFINITY};
    float lrow[4] = {0.f, 0.f, 0.f, 0.f};
    f32x4 oacc[4] = {};

    for (int t = 0; t < SEQ / ATK; ++t) {
        const int cur = t & 1;
        const int kt0 = t * ATK;
        if (t + 1 < SEQ / ATK) {          // prefetch next K/V tile
            const int kn = kt0 + ATK;
            glds16(Kb + kbase + (size_t)kn * HD + dl, Ks[cur ^ 1] + dl);
            glds16(Kb + kbase + (size_t)(kn + 32) * HD + dl, Ks[cur ^ 1] + 2048 + dl);
            glds16(Vtb + vbase + (size_t)vr * SEQ + kn + vc, Vt[cur ^ 1] + dl);
            glds16(Vtb + vbase + (size_t)(vr + 32) * SEQ + kn + vc, Vt[cur ^ 1] + 2048 + dl);
        }

        // ---- S = Q K^T  (4 j-tiles of 16 keys)
        f32x4 s[4] = {};
#pragma unroll
        for (int j = 0; j < 4; ++j) {
            const int row = j * 16 + lr;
            const int sw = (row & 7) << 3;
            bf16x8 b0 = *(const bf16x8*)(Ks[cur] + row * HD + ((quad * 8) ^ sw));
            bf16x8 b1 = *(const bf16x8*)(Ks[cur] + row * HD + ((32 + quad * 8) ^ sw));
            s[j] = __builtin_amdgcn_mfma_f32_16x16x32_bf16(qf0, b0, s[j], 0, 0, 0);
            s[j] = __builtin_amdgcn_mfma_f32_16x16x32_bf16(qf1, b1, s[j], 0, 0, 0);
        }

        // ---- bias + online softmax (rows quad*4+r, cols j*16+lr)
        float pv[4][4];
        float rmax[4] = {-INFINITY, -INFINITY, -INFINITY, -INFINITY};
#pragma unroll
        for (int j = 0; j < 4; ++j) {
            const int kpos = kt0 + j * 16 + lr;
#pragma unroll
            for (int r = 0; r < 4; ++r) {
                float dist = (float)(qpos + r - kpos);
                float val = s[j][r] * 0.125f + slope * fmaxf(dist, 0.0f);
                pv[j][r] = val;
                rmax[r] = fmaxf(rmax[r], val);
            }
        }
#pragma unroll
        for (int off = 1; off <= 8; off <<= 1) {
#pragma unroll
            for (int r = 0; r < 4; ++r)
                rmax[r] = fmaxf(rmax[r], __shfl_xor(rmax[r], off));
        }
        float alpha[4], rsum[4] = {0.f, 0.f, 0.f, 0.f};
#pragma unroll
        for (int r = 0; r < 4; ++r) {
            float mnew = fmaxf(mrow[r], rmax[r]);
            alpha[r] = __expf(mrow[r] - mnew);
            mrow[r] = mnew;
        }
#pragma unroll
        for (int j = 0; j < 4; ++j)
#pragma unroll
            for (int r = 0; r < 4; ++r) {
                float e = __expf(pv[j][r] - mrow[r]);
                pv[j][r] = e;
                rsum[r] += e;
            }
#pragma unroll
        for (int off = 1; off <= 8; off <<= 1) {
#pragma unroll
            for (int r = 0; r < 4; ++r)
                rsum[r] += __shfl_xor(rsum[r], off);
        }
#pragma unroll
        for (int r = 0; r < 4; ++r)
            lrow[r] = lrow[r] * alpha[r] + rsum[r];
#pragma unroll
        for (int n = 0; n < 4; ++n)
#pragma unroll
            for (int r = 0; r < 4; ++r)
                oacc[n][r] *= alpha[r];

        // ---- P -> LDS (wave-local rows: no barrier needed)
#pragma unroll
        for (int j = 0; j < 4; ++j)
#pragma unroll
            for (int r = 0; r < 4; ++r)
                Ps[(wave * 16 + quad * 4 + r) * APAD + j * 16 + lr] = (short)f2bf(pv[j][r]);

        // ---- O += P V
        bf16x8 p0 = *(const bf16x8*)(Ps + (wave * 16 + lr) * APAD + (quad << 3));
        bf16x8 p1 = *(const bf16x8*)(Ps + (wave * 16 + lr) * APAD + 32 + (quad << 3));
#pragma unroll
        for (int n = 0; n < 4; ++n) {
            const int row = n * 16 + lr;
            const int sw = (row & 7) << 3;
            bf16x8 b0 = *(const bf16x8*)(Vt[cur] + row * HD + ((quad * 8) ^ sw));
            bf16x8 b1 = *(const bf16x8*)(Vt[cur] + row * HD + ((32 + quad * 8) ^ sw));
            oacc[n] = __builtin_amdgcn_mfma_f32_16x16x32_bf16(p0, b0, oacc[n], 0, 0, 0);
            oacc[n] = __builtin_amdgcn_mfma_f32_16x16x32_bf16(p1, b1, oacc[n], 0, 0, 0);
        }
        __syncthreads();   // drains prefetch vmcnt; all waves done with buf[cur]
    }

    // ---- epilogue: normalize, write bf16
    float inv[4];
#pragma unroll
    for (int r = 0; r < 4; ++r) inv[r] = 1.0f / lrow[r];
#pragma unroll
    for (int n = 0; n < 4; ++n)
#pragma unroll
        for (int r = 0; r < 4; ++r)
            ob[(size_t)(b * SEQ + qpos + r) * DMODEL + (size_t)h * HD + n * 16 + lr] =
                (short)f2bf(oacc[n][r] * inv[r]);
}

// ---------------------------------------------------------------- residual + LayerNorm (+ bf16 mirror)
__global__ __launch_bounds__(256) void add_ln_kernel(
    const float* __restrict__ x, const float* __restrict__ r,
    const float* __restrict__ g, const float* __restrict__ b,
    float* __restrict__ out, short* __restrict__ outb)
{
    __shared__ float rs[4], rq[4], stats[2];
    const int row = blockIdx.x, tid = threadIdx.x;
    const int c = tid << 2;
    float4 v = *(const float4*)(x + (size_t)row * DMODEL + c);
    if (r) {
        float4 rv = *(const float4*)(r + (size_t)row * DMODEL + c);
        v.x += rv.x; v.y += rv.y; v.z += rv.z; v.w += rv.w;
    }
    float s = v.x + v.y + v.z + v.w;
    float q2 = v.x * v.x + v.y * v.y + v.z * v.z + v.w * v.w;
#pragma unroll
    for (int off = 32; off; off >>= 1) {
        s += __shfl_down(s, off, 64);
        q2 += __shfl_down(q2, off, 64);
    }
    const int wid = tid >> 6, lane = tid & 63;
    if (lane == 0) { rs[wid] = s; rq[wid] = q2; }
    __syncthreads();
    if (tid == 0) {
        float ts = rs[0] + rs[1] + rs[2] + rs[3];
        float tq = rq[0] + rq[1] + rq[2] + rq[3];
        float mean = ts * (1.0f / DMODEL);
        stats[0] = mean;
        stats[1] = rsqrtf(tq * (1.0f / DMODEL) - mean * mean + LNEPS);
    }
    __syncthreads();
    const float mean = stats[0], rstd = stats[1];
    float4 gv = *(const float4*)(g + c);
    float4 bv = *(const float4*)(b + c);
    float4 res;
    res.x = (v.x - mean) * rstd * gv.x + bv.x;
    res.y = (v.y - mean) * rstd * gv.y + bv.y;
    res.z = (v.z - mean) * rstd * gv.z + bv.z;
    res.w = (v.w - mean) * rstd * gv.w + bv.w;
    *(float4*)(out + (size_t)row * DMODEL + c) = res;
    if (outb) {
        uint2 p;
        p.x = (unsigned)f2bf(res.x) | ((unsigned)f2bf(res.y) << 16);
        p.y = (unsigned)f2bf(res.z) | ((unsigned)f2bf(res.w) << 16);
        *(uint2*)(outb + (size_t)row * DMODEL + c) = p;
    }
}

// ---------------------------------------------------------------- host
extern "C" void kernel_launch(void* const* d_in, const int* in_sizes, int n_in,
                              void* d_out, int out_size, void* d_ws, size_t ws_size,
                              hipStream_t stream)
{
    (void)in_sizes; (void)n_in; (void)out_size; (void)ws_size;
    const float* src = (const float*)d_in[0];
    const float* Wq  = (const float*)d_in[1];
    const float* bq  = (const float*)d_in[2];
    const float* Wk  = (const float*)d_in[3];
    const float* bk  = (const float*)d_in[4];
    const float* Wv  = (const float*)d_in[5];
    const float* bv  = (const float*)d_in[6];
    const float* Wo  = (const float*)d_in[7];
    const float* bo  = (const float*)d_in[8];
    const float* W1  = (const float*)d_in[9];
    const float* b1  = (const float*)d_in[10];
    const float* W2  = (const float*)d_in[11];
    const float* b2  = (const float*)d_in[12];
    const float* g1  = (const float*)d_in[13];
    const float* be1 = (const float*)d_in[14];
    const float* g2  = (const float*)d_in[15];
    const float* be2 = (const float*)d_in[16];
    const float* gf  = (const float*)d_in[17];
    const float* bfp = (const float*)d_in[18];
    float* out = (float*)d_out;

    char* p = (char*)d_ws;
    auto carve = [&](size_t bytes) -> char* {
        char* r = p; p += (bytes + 255) & ~(size_t)255; return r;
    };
    float* x    = (float*)carve((size_t)MROWS * DMODEL * 4);
    float* t1   = (float*)carve((size_t)MROWS * DMODEL * 4);
    float* xqkv = (float*)carve((size_t)MROWS * LDQ * 4);
    float* pe   = (float*)carve((size_t)SEQ * HD * 4);
    float* bqkv = (float*)carve((size_t)LDQ * 4);
    short* xb   = (short*)carve((size_t)MROWS * DMODEL * 2);
    short* obb  = (short*)carve((size_t)MROWS * DMODEL * 2);
    short* h1b  = (short*)carve((size_t)MROWS * FFD * 2);
    short* wtqkv= (short*)carve((size_t)3 * DMODEL * DMODEL * 2);
    short* wto  = (short*)carve((size_t)DMODEL * DMODEL * 2);
    short* wt1  = (short*)carve((size_t)DMODEL * FFD * 2);
    short* wt2  = (short*)carve((size_t)DMODEL * FFD * 2);
    short* qbb  = (short*)carve((size_t)MROWS * DMODEL * 2);
    short* kbb  = (short*)carve((size_t)MROWS * DMODEL * 2);
    short* vtb  = (short*)carve((size_t)MROWS * DMODEL * 2);

    hipMemcpyAsync(x, src, (size_t)MROWS * DMODEL * 4, hipMemcpyDeviceToDevice, stream);
    conv_bf16<<<MROWS * DMODEL / 4 / 256, 256, 0, stream>>>(src, xb, MROWS * DMODEL);
    pe_fill<<<SEQ, HD, 0, stream>>>(pe);

    const size_t DD = (size_t)DMODEL * DMODEL;
    for (int l = 0; l < NLAYERS; ++l) {
        transpose_bf16<<<dim3(32, 32), 256, 0, stream>>>(Wq + l * DD, wtqkv,          DMODEL, DMODEL);
        transpose_bf16<<<dim3(32, 32), 256, 0, stream>>>(Wk + l * DD, wtqkv + DD,     DMODEL, DMODEL);
        transpose_bf16<<<dim3(32, 32), 256, 0, stream>>>(Wv + l * DD, wtqkv + 2 * DD, DMODEL, DMODEL);
        transpose_bf16<<<dim3(32, 32), 256, 0, stream>>>(Wo + l * DD, wto, DMODEL, DMODEL);
        transpose_bf16<<<dim3(128, 32), 256, 0, stream>>>(W1 + (size_t)l * DMODEL * FFD, wt1, DMODEL, FFD);
        transpose_bf16<<<dim3(32, 128), 256, 0, stream>>>(W2 + (size_t)l * FFD * DMODEL, wt2, FFD, DMODEL);
        stack_bias<<<12, 256, 0, stream>>>(bq + l * DMODEL, bk + l * DMODEL, bv + l * DMODEL, bqkv);

        gemm_tn<128><<<dim3(LDQ / 128, MROWS / 128), 256, 0, stream>>>(
            xb, wtqkv, bqkv, xqkv, nullptr, MROWS, LDQ, DMODEL, LDQ, 0);
        ropeconv<<<dim3(16, 16, 2), 256, 0, stream>>>(xqkv, pe, qbb, kbb, vtb);
        attn_mfma<<<BATCH * NH * (SEQ / ATQ), 256, 0, stream>>>(qbb, kbb, vtb, obb);
        gemm_tn<64><<<dim3(DMODEL / 64, MROWS / 128), 256, 0, stream>>>(
            obb, wto, bo + l * DMODEL, t1, nullptr, MROWS, DMODEL, DMODEL, DMODEL, 0);
        add_ln_kernel<<<MROWS, 256, 0, stream>>>(x, t1, g1 + l * DMODEL, be1 + l * DMODEL, x, xb);
        gemm_tn<128><<<dim3(FFD / 128, MROWS / 128), 256, 0, stream>>>(
            xb, wt1, b1 + l * FFD, nullptr, h1b, MROWS, FFD, DMODEL, FFD, 1);
        gemm_tn<64><<<dim3(DMODEL / 64, MROWS / 128), 256, 0, stream>>>(
            h1b, wt2, b2 + l * DMODEL, t1, nullptr, MROWS, DMODEL, FFD, DMODEL, 0);
        add_ln_kernel<<<MROWS, 256, 0, stream>>>(x, t1, g2 + l * DMODEL, be2 + l * DMODEL, x, xb);
    }
    add_ln_kernel<<<MROWS, 256, 0, stream>>>(x, nullptr, gf, bfp, out, nullptr);
}

// Round 4
// 2030.288 us; speedup vs baseline: 1.3109x; 1.0636x over previous
//
#include <hip/hip_runtime.h>
#include <hip/hip_bf16.h>
#include <math.h>

#define NLAYERS 8
#define DMODEL 1024
#define NH 16
#define HD 64
#define FFD 4096
#define SEQ 1024
#define BATCH 2
#define MROWS (BATCH * SEQ)   // 2048
#define LNEPS 1e-5f
#define LDQ 3072              // fused qkv row stride

typedef short bf16x8 __attribute__((ext_vector_type(8)));
typedef float f32x4 __attribute__((ext_vector_type(4)));

__device__ __forceinline__ unsigned short f2bf(float v) {
    unsigned u = __float_as_uint(v);
    u += 0x7fffu + ((u >> 16) & 1u);   // RNE
    return (unsigned short)(u >> 16);
}

__device__ __forceinline__ float gelu_exact(float x) {
    return 0.5f * x * (1.0f + erff(x * 0.70710678118654752f));
}

// async global->LDS, 16B per lane. LDS dest must be linear in lane order.
__device__ __forceinline__ void glds16(const short* g, short* l) {
    __builtin_amdgcn_global_load_lds(
        (const __attribute__((address_space(1))) unsigned*)g,
        (__attribute__((address_space(3))) unsigned*)l, 16, 0, 0);
}

// ---------------------------------------------------------------- MFMA GEMM (TN, split-K)
// C_part[z][M,N] = A[M, z*Ksub : (z+1)*Ksub] @ Bt[N, same]^T  (+bias on z==0).
// blockIdx.z = K-split index; partial z writes Cf + z*pstride (f32).
// Double-buffered LDS, global_load_lds prefetch of tile t+1 before MFMA of t.
#define TKT 32

template<int BN>
__global__ __launch_bounds__(256) void gemm_tn(
    const short* __restrict__ A, const short* __restrict__ Bt,
    const float* __restrict__ bias, float* __restrict__ Cf,
    short* __restrict__ Cb, int M, int N, int K, int Ksub,
    size_t pstride, int ldc, int act)
{
    constexpr int BM = 128;
    constexpr int MR = (BN == 128) ? 4 : 2;   // 16-row frags per wave
    constexpr int NR = 4;                     // 16-col frags per wave
    __shared__ __align__(16) short As[2][BM * TKT];
    __shared__ __align__(16) short Bs[2][BN * TKT];

    const int tid = threadIdx.x;
    const int bm = blockIdx.y * BM;
    const int bn = blockIdx.x * BN;
    const int kz = blockIdx.z;
    const int wave = tid >> 6, lane = tid & 63;
    const int lr = lane & 15, quad = lane >> 4;
    const int wm = (BN == 128) ? ((wave >> 1) << 6) : (wave << 5);
    const int wn = (BN == 128) ? ((wave & 1) << 6) : 0;

    const int srow = tid >> 2;            // 0..63
    const int scol = (tid & 3) << 3;      // 0,8,16,24 (bf16 elems)
    const short* ag = A  + (size_t)(bm + srow) * K + kz * Ksub + scol;
    const short* bg = Bt + (size_t)(bn + srow) * K + kz * Ksub + scol;
    const int soff = srow * TKT + scol;   // = tid*8 shorts: linear in lane order
    float* cf = Cf ? Cf + (size_t)kz * pstride : nullptr;

    f32x4 acc[MR][NR] = {};
    const int nk = Ksub / TKT;

    // prologue: stage tile 0
    glds16(ag, As[0] + soff);
    glds16(ag + (size_t)64 * K, As[0] + soff + 64 * TKT);
    glds16(bg, Bs[0] + soff);
    if constexpr (BN == 128) glds16(bg + (size_t)64 * K, Bs[0] + soff + 64 * TKT);
    asm volatile("s_waitcnt vmcnt(0)" ::: "memory");
    __builtin_amdgcn_s_barrier();

    for (int t = 0; t < nk; ++t) {
        const int cur = t & 1;
        if (t + 1 < nk) {                 // prefetch tile t+1 (overlaps MFMA below)
            const int k0 = (t + 1) * TKT;
            glds16(ag + k0, As[cur ^ 1] + soff);
            glds16(ag + (size_t)64 * K + k0, As[cur ^ 1] + soff + 64 * TKT);
            glds16(bg + k0, Bs[cur ^ 1] + soff);
            if constexpr (BN == 128)
                glds16(bg + (size_t)64 * K + k0, Bs[cur ^ 1] + soff + 64 * TKT);
        }
        bf16x8 af[MR], bfr[NR];
#pragma unroll
        for (int i = 0; i < MR; ++i)
            af[i]  = *(const bf16x8*)(As[cur] + (wm + i * 16 + lr) * TKT + (quad << 3));
#pragma unroll
        for (int j = 0; j < NR; ++j)
            bfr[j] = *(const bf16x8*)(Bs[cur] + (wn + j * 16 + lr) * TKT + (quad << 3));
#pragma unroll
        for (int i = 0; i < MR; ++i)
#pragma unroll
            for (int j = 0; j < NR; ++j)
                acc[i][j] = __builtin_amdgcn_mfma_f32_16x16x32_bf16(
                    af[i], bfr[j], acc[i][j], 0, 0, 0);
        asm volatile("s_waitcnt vmcnt(0)" ::: "memory");   // t+1 loads landed
        __builtin_amdgcn_s_barrier();
    }
#pragma unroll
    for (int j = 0; j < NR; ++j) {
        const int col = bn + wn + j * 16 + lr;
        const float bj = (kz == 0) ? bias[col] : 0.0f;
#pragma unroll
        for (int i = 0; i < MR; ++i) {
            const int rowb = bm + wm + i * 16 + (quad << 2);
#pragma unroll
            for (int r = 0; r < 4; ++r) {
                float v = acc[i][j][r] + bj;
                if (act) v = gelu_exact(v);
                if (Cb) Cb[(size_t)(rowb + r) * ldc + col] = (short)f2bf(v);
                else    cf[(size_t)(rowb + r) * ldc + col] = v;
            }
        }
    }
}

// ---------------------------------------------------------------- transpose + fp32->bf16
__global__ __launch_bounds__(256) void transpose_bf16(
    const float* __restrict__ in, short* __restrict__ out, int R, int C)
{
    __shared__ float t[32][33];
    const int tid = threadIdx.x;
    const int rt = blockIdx.y << 5, ct = blockIdx.x << 5;
    const int r = tid >> 3, c4 = (tid & 7) << 2;
    float4 v = *(const float4*)(in + (size_t)(rt + r) * C + ct + c4);
    t[r][c4 + 0] = v.x; t[r][c4 + 1] = v.y; t[r][c4 + 2] = v.z; t[r][c4 + 3] = v.w;
    __syncthreads();
    unsigned short s0 = f2bf(t[c4 + 0][r]);
    unsigned short s1 = f2bf(t[c4 + 1][r]);
    unsigned short s2 = f2bf(t[c4 + 2][r]);
    unsigned short s3 = f2bf(t[c4 + 3][r]);
    uint2 p;
    p.x = (unsigned)s0 | ((unsigned)s1 << 16);
    p.y = (unsigned)s2 | ((unsigned)s3 << 16);
    *(uint2*)(out + (size_t)(ct + r) * R + rt + c4) = p;
}

// ---------------------------------------------------------------- small utils
__global__ void stack_bias(const float* __restrict__ bq, const float* __restrict__ bk,
                           const float* __restrict__ bv, float* __restrict__ out)
{
    int i = blockIdx.x * 256 + threadIdx.x;   // 0..3071
    float v = (i < 1024) ? bq[i] : (i < 2048) ? bk[i - 1024] : bv[i - 2048];
    out[i] = v;
}

__global__ void conv_bf16(const float* __restrict__ in, short* __restrict__ out, int n)
{
    int i = (blockIdx.x * 256 + threadIdx.x) << 2;
    if (i < n) {
        float4 v = *(const float4*)(in + i);
        uint2 p;
        p.x = (unsigned)f2bf(v.x) | ((unsigned)f2bf(v.y) << 16);
        p.y = (unsigned)f2bf(v.z) | ((unsigned)f2bf(v.w) << 16);
        *(uint2*)(out + i) = p;
    }
}

// ---------------------------------------------------------------- PE table
__global__ void pe_fill(float* __restrict__ pe)
{
    int pos = blockIdx.x;
    int i = threadIdx.x;            // 0..63
    int j = i & 31;
    float invf = powf(10000.0f, -(float)j / 32.0f);
    float a = (float)pos * invf;
    pe[pos * HD + i] = (i < 32) ? cosf(a) : sinf(a);
}

// ---------------------------------------------------------------- RoPE + bf16 convert + V transpose
// Reads fused qkv as sum of two split-K partials (fp32), writes:
//   Qb,Kb : [B][H][S][64] bf16, roped, rows XOR-swizzled (chunk16B ^ (s&7)<<4)
//   Vtb   : [B][H][64][S] bf16, transposed, segments XOR-swizzled by (hd&7)
__global__ __launch_bounds__(256) void ropeconv(
    const float* __restrict__ xqkv, const float* __restrict__ xqkv1,
    const float* __restrict__ pe,
    short* __restrict__ Qb, short* __restrict__ Kb, short* __restrict__ Vtb)
{
    __shared__ __align__(16) short Vl[HD * 72];   // [hd][s] transpose staging

    const int stile = blockIdx.x;     // 0..15
    const int h = blockIdx.y;         // 0..15
    const int b = blockIdx.z;         // 0..1
    const int tid = threadIdx.x;
    const int srow = tid >> 2;        // 0..63
    const int c0 = (tid & 3) << 4;    // output head-dims [c0, c0+16)
    const int s = stile * 64 + srow;
    const size_t xoff = (size_t)(b * SEQ + s) * LDQ + h * HD;
    const int e0 = (c0 & 31) << 1;    // input dim base

    const float* px0 = xqkv + xoff;               // q part0
    const float* px1 = xqkv1 + xoff;              // q part1
    const float* pk0 = xqkv + DMODEL + xoff;      // k part0
    const float* pk1 = xqkv1 + DMODEL + xoff;     // k part1
    const float* pp = pe + s * HD + e0;
    float qv[32], kv[32], pv[32];
#pragma unroll
    for (int i = 0; i < 32; i += 4) {
        float4 a = *(const float4*)(px0 + e0 + i);
        float4 a1 = *(const float4*)(px1 + e0 + i);
        a.x += a1.x; a.y += a1.y; a.z += a1.z; a.w += a1.w;
        *(float4*)(qv + i) = a;
        float4 k = *(const float4*)(pk0 + e0 + i);
        float4 k1 = *(const float4*)(pk1 + e0 + i);
        k.x += k1.x; k.y += k1.y; k.z += k1.z; k.w += k1.w;
        *(float4*)(kv + i) = k;
        *(float4*)(pv + i) = *(const float4*)(pp + i);
    }
    bf16x8 oq[2], ok[2];
#pragma unroll
    for (int i = 0; i < 16; ++i) {
        float qa = qv[2 * i], qb2 = qv[2 * i + 1];
        float ka = kv[2 * i], kb2 = kv[2 * i + 1];
        float cc = pv[2 * i], ss = pv[2 * i + 1];
        float rq = (c0 < 32) ? qa * cc - qb2 * ss : qa * ss + qb2 * cc;
        float rk = (c0 < 32) ? ka * cc - kb2 * ss : ka * ss + kb2 * cc;
        oq[i >> 3][i & 7] = (short)f2bf(rq);
        ok[i >> 3][i & 7] = (short)f2bf(rk);
    }
    const size_t obase = ((size_t)(b * NH + h) * SEQ + s) * HD;
    const int sw = (s & 7) << 3;      // swizzle in shorts
    *(bf16x8*)(Qb + obase + (c0 ^ sw))       = oq[0];
    *(bf16x8*)(Qb + obase + ((c0 + 8) ^ sw)) = oq[1];
    *(bf16x8*)(Kb + obase + (c0 ^ sw))       = ok[0];
    *(bf16x8*)(Kb + obase + ((c0 + 8) ^ sw)) = ok[1];

    // V: sum partials, convert + transpose via LDS
    {
        const float* pv0 = xqkv + 2 * DMODEL + xoff;
        const float* pv1 = xqkv1 + 2 * DMODEL + xoff;
        float vv[16];
#pragma unroll
        for (int i = 0; i < 16; i += 4) {
            float4 a = *(const float4*)(pv0 + c0 + i);
            float4 a1 = *(const float4*)(pv1 + c0 + i);
            a.x += a1.x; a.y += a1.y; a.z += a1.z; a.w += a1.w;
            *(float4*)(vv + i) = a;
        }
#pragma unroll
        for (int i = 0; i < 16; ++i)
            Vl[(c0 + i) * 72 + srow] = (short)f2bf(vv[i]);
    }
    __syncthreads();
    {
        const int r = tid >> 2;               // hd 0..63
        const int cb = (tid & 3) << 4;        // s-chunk base within tile (shorts)
        bf16x8 w0 = *(const bf16x8*)(Vl + r * 72 + cb);
        bf16x8 w1 = *(const bf16x8*)(Vl + r * 72 + cb + 8);
        const int swv = (r & 7) << 3;
        const size_t vb = ((size_t)(b * NH + h) * HD + r) * SEQ + stile * 64;
        *(bf16x8*)(Vtb + vb + (cb ^ swv))       = w0;
        *(bf16x8*)(Vtb + vb + ((cb + 8) ^ swv)) = w1;
    }
}

// ---------------------------------------------------------------- MFMA flash attention
#define ATQ 64
#define ATK 64
#define APAD 72

__global__ __launch_bounds__(256) void attn_mfma(
    const short* __restrict__ Qb, const short* __restrict__ Kb,
    const short* __restrict__ Vtb, short* __restrict__ ob)
{
    __shared__ __align__(16) short Qs[ATQ * HD];
    __shared__ __align__(16) short Ks[2][ATK * HD];
    __shared__ __align__(16) short Vt[2][HD * ATK];
    __shared__ __align__(16) short Ps[ATQ * APAD];

    const int tid = threadIdx.x;
    const int bid = blockIdx.x;
    const int qtile = bid & 15;
    const int h = (bid >> 4) & 15;
    const int b = bid >> 8;
    const int q0 = qtile * ATQ;
    const int bh = b * NH + h;
    const size_t qbase = ((size_t)bh * SEQ + q0) * HD;
    const size_t kbase = (size_t)bh * SEQ * HD;
    const size_t vbase = (size_t)bh * HD * SEQ;

    const int wave = tid >> 6, lane = tid & 63;
    const int lr = lane & 15, quad = lane >> 4;
    const int dl = tid * 8;            // shorts: linear lane-order LDS dest
    const int vr = tid >> 3;           // 0..31 (row within 32-row half)
    const int vc = (tid & 7) * 8;      // col chunk (shorts)

    // ---- prologue: stage Q + K/V tile 0
    glds16(Qb + qbase + dl, Qs + dl);
    glds16(Qb + qbase + 2048 + dl, Qs + 2048 + dl);
    glds16(Kb + kbase + dl, Ks[0] + dl);
    glds16(Kb + kbase + 32 * HD + dl, Ks[0] + 2048 + dl);
    glds16(Vtb + vbase + (size_t)vr * SEQ + vc, Vt[0] + dl);
    glds16(Vtb + vbase + (size_t)(vr + 32) * SEQ + vc, Vt[0] + 2048 + dl);
    __syncthreads();

    bf16x8 qf0, qf1;
    {
        const int row = wave * 16 + lr;
        const int sw = (row & 7) << 3;
        qf0 = *(const bf16x8*)(Qs + row * HD + ((quad * 8) ^ sw));
        qf1 = *(const bf16x8*)(Qs + row * HD + ((32 + quad * 8) ^ sw));
    }

    const float slope = exp2f(-0.5f * (float)h);
    const int qpos = q0 + wave * 16 + quad * 4;   // +r
    float mrow[4] = {-INFINITY, -INFINITY, -INFINITY, -INFINITY};
    float lrow[4] = {0.f, 0.f, 0.f, 0.f};
    f32x4 oacc[4] = {};

    for (int t = 0; t < SEQ / ATK; ++t) {
        const int cur = t & 1;
        const int kt0 = t * ATK;
        if (t + 1 < SEQ / ATK) {          // prefetch next K/V tile
            const int kn = kt0 + ATK;
            glds16(Kb + kbase + (size_t)kn * HD + dl, Ks[cur ^ 1] + dl);
            glds16(Kb + kbase + (size_t)(kn + 32) * HD + dl, Ks[cur ^ 1] + 2048 + dl);
            glds16(Vtb + vbase + (size_t)vr * SEQ + kn + vc, Vt[cur ^ 1] + dl);
            glds16(Vtb + vbase + (size_t)(vr + 32) * SEQ + kn + vc, Vt[cur ^ 1] + 2048 + dl);
        }

        // ---- S = Q K^T  (4 j-tiles of 16 keys)
        f32x4 s[4] = {};
#pragma unroll
        for (int j = 0; j < 4; ++j) {
            const int row = j * 16 + lr;
            const int sw = (row & 7) << 3;
            bf16x8 b0 = *(const bf16x8*)(Ks[cur] + row * HD + ((quad * 8) ^ sw));
            bf16x8 b1 = *(const bf16x8*)(Ks[cur] + row * HD + ((32 + quad * 8) ^ sw));
            s[j] = __builtin_amdgcn_mfma_f32_16x16x32_bf16(qf0, b0, s[j], 0, 0, 0);
            s[j] = __builtin_amdgcn_mfma_f32_16x16x32_bf16(qf1, b1, s[j], 0, 0, 0);
        }

        // ---- bias + online softmax (rows quad*4+r, cols j*16+lr)
        float pv[4][4];
        float rmax[4] = {-INFINITY, -INFINITY, -INFINITY, -INFINITY};
#pragma unroll
        for (int j = 0; j < 4; ++j) {
            const int kpos = kt0 + j * 16 + lr;
#pragma unroll
            for (int r = 0; r < 4; ++r) {
                float dist = (float)(qpos + r - kpos);
                float val = s[j][r] * 0.125f + slope * fmaxf(dist, 0.0f);
                pv[j][r] = val;
                rmax[r] = fmaxf(rmax[r], val);
            }
        }
#pragma unroll
        for (int off = 1; off <= 8; off <<= 1) {
#pragma unroll
            for (int r = 0; r < 4; ++r)
                rmax[r] = fmaxf(rmax[r], __shfl_xor(rmax[r], off));
        }
        float alpha[4], rsum[4] = {0.f, 0.f, 0.f, 0.f};
#pragma unroll
        for (int r = 0; r < 4; ++r) {
            float mnew = fmaxf(mrow[r], rmax[r]);
            alpha[r] = __expf(mrow[r] - mnew);
            mrow[r] = mnew;
        }
#pragma unroll
        for (int j = 0; j < 4; ++j)
#pragma unroll
            for (int r = 0; r < 4; ++r) {
                float e = __expf(pv[j][r] - mrow[r]);
                pv[j][r] = e;
                rsum[r] += e;
            }
#pragma unroll
        for (int off = 1; off <= 8; off <<= 1) {
#pragma unroll
            for (int r = 0; r < 4; ++r)
                rsum[r] += __shfl_xor(rsum[r], off);
        }
#pragma unroll
        for (int r = 0; r < 4; ++r)
            lrow[r] = lrow[r] * alpha[r] + rsum[r];
#pragma unroll
        for (int n = 0; n < 4; ++n)
#pragma unroll
            for (int r = 0; r < 4; ++r)
                oacc[n][r] *= alpha[r];

        // ---- P -> LDS (wave-local rows: no barrier needed)
#pragma unroll
        for (int j = 0; j < 4; ++j)
#pragma unroll
            for (int r = 0; r < 4; ++r)
                Ps[(wave * 16 + quad * 4 + r) * APAD + j * 16 + lr] = (short)f2bf(pv[j][r]);

        // ---- O += P V
        bf16x8 p0 = *(const bf16x8*)(Ps + (wave * 16 + lr) * APAD + (quad << 3));
        bf16x8 p1 = *(const bf16x8*)(Ps + (wave * 16 + lr) * APAD + 32 + (quad << 3));
#pragma unroll
        for (int n = 0; n < 4; ++n) {
            const int row = n * 16 + lr;
            const int sw = (row & 7) << 3;
            bf16x8 b0 = *(const bf16x8*)(Vt[cur] + row * HD + ((quad * 8) ^ sw));
            bf16x8 b1 = *(const bf16x8*)(Vt[cur] + row * HD + ((32 + quad * 8) ^ sw));
            oacc[n] = __builtin_amdgcn_mfma_f32_16x16x32_bf16(p0, b0, oacc[n], 0, 0, 0);
            oacc[n] = __builtin_amdgcn_mfma_f32_16x16x32_bf16(p1, b1, oacc[n], 0, 0, 0);
        }
        __syncthreads();   // drains prefetch vmcnt; all waves done with buf[cur]
    }

    // ---- epilogue: normalize, write bf16
    float inv[4];
#pragma unroll
    for (int r = 0; r < 4; ++r) inv[r] = 1.0f / lrow[r];
#pragma unroll
    for (int n = 0; n < 4; ++n)
#pragma unroll
        for (int r = 0; r < 4; ++r)
            ob[(size_t)(b * SEQ + qpos + r) * DMODEL + (size_t)h * HD + n * 16 + lr] =
                (short)f2bf(oacc[n][r] * inv[r]);
}

// ---------------------------------------------------------------- residual + LayerNorm (+ bf16 mirror)
// Sums x + up to 4 partial residual streams (split-K GEMM outputs).
__global__ __launch_bounds__(256) void add_ln_kernel(
    const float* __restrict__ x, const float* __restrict__ r,
    const float* __restrict__ r2, const float* __restrict__ r3,
    const float* __restrict__ r4,
    const float* __restrict__ g, const float* __restrict__ b,
    float* __restrict__ out, short* __restrict__ outb)
{
    __shared__ float rs[4], rq[4], stats[2];
    const int row = blockIdx.x, tid = threadIdx.x;
    const int c = tid << 2;
    const size_t off = (size_t)row * DMODEL + c;
    float4 v = *(const float4*)(x + off);
    if (r) {
        float4 rv = *(const float4*)(r + off);
        v.x += rv.x; v.y += rv.y; v.z += rv.z; v.w += rv.w;
    }
    if (r2) {
        float4 rv = *(const float4*)(r2 + off);
        v.x += rv.x; v.y += rv.y; v.z += rv.z; v.w += rv.w;
    }
    if (r3) {
        float4 rv = *(const float4*)(r3 + off);
        v.x += rv.x; v.y += rv.y; v.z += rv.z; v.w += rv.w;
    }
    if (r4) {
        float4 rv = *(const float4*)(r4 + off);
        v.x += rv.x; v.y += rv.y; v.z += rv.z; v.w += rv.w;
    }
    float s = v.x + v.y + v.z + v.w;
    float q2 = v.x * v.x + v.y * v.y + v.z * v.z + v.w * v.w;
#pragma unroll
    for (int off2 = 32; off2; off2 >>= 1) {
        s += __shfl_down(s, off2, 64);
        q2 += __shfl_down(q2, off2, 64);
    }
    const int wid = tid >> 6, lane = tid & 63;
    if (lane == 0) { rs[wid] = s; rq[wid] = q2; }
    __syncthreads();
    if (tid == 0) {
        float ts = rs[0] + rs[1] + rs[2] + rs[3];
        float tq = rq[0] + rq[1] + rq[2] + rq[3];
        float mean = ts * (1.0f / DMODEL);
        stats[0] = mean;
        stats[1] = rsqrtf(tq * (1.0f / DMODEL) - mean * mean + LNEPS);
    }
    __syncthreads();
    const float mean = stats[0], rstd = stats[1];
    float4 gv = *(const float4*)(g + c);
    float4 bv = *(const float4*)(b + c);
    float4 res;
    res.x = (v.x - mean) * rstd * gv.x + bv.x;
    res.y = (v.y - mean) * rstd * gv.y + bv.y;
    res.z = (v.z - mean) * rstd * gv.z + bv.z;
    res.w = (v.w - mean) * rstd * gv.w + bv.w;
    *(float4*)(out + off) = res;
    if (outb) {
        uint2 p;
        p.x = (unsigned)f2bf(res.x) | ((unsigned)f2bf(res.y) << 16);
        p.y = (unsigned)f2bf(res.z) | ((unsigned)f2bf(res.w) << 16);
        *(uint2*)(outb + off) = p;
    }
}

// ---------------------------------------------------------------- host
extern "C" void kernel_launch(void* const* d_in, const int* in_sizes, int n_in,
                              void* d_out, int out_size, void* d_ws, size_t ws_size,
                              hipStream_t stream)
{
    (void)in_sizes; (void)n_in; (void)out_size; (void)ws_size;
    const float* src = (const float*)d_in[0];
    const float* Wq  = (const float*)d_in[1];
    const float* bq  = (const float*)d_in[2];
    const float* Wk  = (const float*)d_in[3];
    const float* bk  = (const float*)d_in[4];
    const float* Wv  = (const float*)d_in[5];
    const float* bv  = (const float*)d_in[6];
    const float* Wo  = (const float*)d_in[7];
    const float* bo  = (const float*)d_in[8];
    const float* W1  = (const float*)d_in[9];
    const float* b1  = (const float*)d_in[10];
    const float* W2  = (const float*)d_in[11];
    const float* b2  = (const float*)d_in[12];
    const float* g1  = (const float*)d_in[13];
    const float* be1 = (const float*)d_in[14];
    const float* g2  = (const float*)d_in[15];
    const float* be2 = (const float*)d_in[16];
    const float* gf  = (const float*)d_in[17];
    const float* bfp = (const float*)d_in[18];
    float* out = (float*)d_out;

    char* p = (char*)d_ws;
    auto carve = [&](size_t bytes) -> char* {
        char* r = p; p += (bytes + 255) & ~(size_t)255; return r;
    };
    float* x    = (float*)carve((size_t)MROWS * DMODEL * 4);
    float* t1   = (float*)carve((size_t)4 * MROWS * DMODEL * 4);   // 4 split-K partials
    float* xqkv = (float*)carve((size_t)2 * MROWS * LDQ * 4);      // 2 split-K partials
    float* pe   = (float*)carve((size_t)SEQ * HD * 4);
    float* bqkv = (float*)carve((size_t)LDQ * 4);
    short* xb   = (short*)carve((size_t)MROWS * DMODEL * 2);
    short* obb  = (short*)carve((size_t)MROWS * DMODEL * 2);
    short* h1b  = (short*)carve((size_t)MROWS * FFD * 2);
    short* wtqkv= (short*)carve((size_t)3 * DMODEL * DMODEL * 2);
    short* wto  = (short*)carve((size_t)DMODEL * DMODEL * 2);
    short* wt1  = (short*)carve((size_t)DMODEL * FFD * 2);
    short* wt2  = (short*)carve((size_t)DMODEL * FFD * 2);
    short* qbb  = (short*)carve((size_t)MROWS * DMODEL * 2);
    short* kbb  = (short*)carve((size_t)MROWS * DMODEL * 2);
    short* vtb  = (short*)carve((size_t)MROWS * DMODEL * 2);

    const size_t TP = (size_t)MROWS * DMODEL;       // t1 partial stride
    const size_t QP = (size_t)MROWS * LDQ;          // xqkv partial stride

    hipMemcpyAsync(x, src, (size_t)MROWS * DMODEL * 4, hipMemcpyDeviceToDevice, stream);
    conv_bf16<<<MROWS * DMODEL / 4 / 256, 256, 0, stream>>>(src, xb, MROWS * DMODEL);
    pe_fill<<<SEQ, HD, 0, stream>>>(pe);

    const size_t DD = (size_t)DMODEL * DMODEL;
    for (int l = 0; l < NLAYERS; ++l) {
        transpose_bf16<<<dim3(32, 32), 256, 0, stream>>>(Wq + l * DD, wtqkv,          DMODEL, DMODEL);
        transpose_bf16<<<dim3(32, 32), 256, 0, stream>>>(Wk + l * DD, wtqkv + DD,     DMODEL, DMODEL);
        transpose_bf16<<<dim3(32, 32), 256, 0, stream>>>(Wv + l * DD, wtqkv + 2 * DD, DMODEL, DMODEL);
        transpose_bf16<<<dim3(32, 32), 256, 0, stream>>>(Wo + l * DD, wto, DMODEL, DMODEL);
        transpose_bf16<<<dim3(128, 32), 256, 0, stream>>>(W1 + (size_t)l * DMODEL * FFD, wt1, DMODEL, FFD);
        transpose_bf16<<<dim3(32, 128), 256, 0, stream>>>(W2 + (size_t)l * FFD * DMODEL, wt2, FFD, DMODEL);
        stack_bias<<<12, 256, 0, stream>>>(bq + l * DMODEL, bk + l * DMODEL, bv + l * DMODEL, bqkv);

        // qkv GEMM: split-K=2 -> 24x16x2 = 768 blocks (3/CU)
        gemm_tn<128><<<dim3(LDQ / 128, MROWS / 128, 2), 256, 0, stream>>>(
            xb, wtqkv, bqkv, xqkv, nullptr, MROWS, LDQ, DMODEL, DMODEL / 2, QP, LDQ, 0);
        ropeconv<<<dim3(16, 16, 2), 256, 0, stream>>>(xqkv, xqkv + QP, pe, qbb, kbb, vtb);
        attn_mfma<<<BATCH * NH * (SEQ / ATQ), 256, 0, stream>>>(qbb, kbb, vtb, obb);
        // attn-out GEMM: split-K=2 -> 16x16x2 = 512 blocks (2/CU)
        gemm_tn<64><<<dim3(DMODEL / 64, MROWS / 128, 2), 256, 0, stream>>>(
            obb, wto, bo + l * DMODEL, t1, nullptr, MROWS, DMODEL, DMODEL, DMODEL / 2, TP, DMODEL, 0);
        add_ln_kernel<<<MROWS, 256, 0, stream>>>(
            x, t1, t1 + TP, nullptr, nullptr, g1 + l * DMODEL, be1 + l * DMODEL, x, xb);
        // FF1: gelu -> cannot split (nonlinear); 32x16 = 512 blocks (2/CU)
        gemm_tn<128><<<dim3(FFD / 128, MROWS / 128, 1), 256, 0, stream>>>(
            xb, wt1, b1 + l * FFD, nullptr, h1b, MROWS, FFD, DMODEL, DMODEL, 0, FFD, 1);
        // FF2: split-K=4 -> 16x16x4 = 1024 blocks (4/CU)
        gemm_tn<64><<<dim3(DMODEL / 64, MROWS / 128, 4), 256, 0, stream>>>(
            h1b, wt2, b2 + l * DMODEL, t1, nullptr, MROWS, DMODEL, FFD, FFD / 4, TP, DMODEL, 0);
        add_ln_kernel<<<MROWS, 256, 0, stream>>>(
            x, t1, t1 + TP, t1 + 2 * TP, t1 + 3 * TP, g2 + l * DMODEL, be2 + l * DMODEL, x, xb);
    }
    add_ln_kernel<<<MROWS, 256, 0, stream>>>(
        x, nullptr, nullptr, nullptr, nullptr, gf, bfp, out, nullptr);
}